// Round 8
// baseline (31022.003 us; speedup 1.0000x reference)
//
#include <hip/hip_runtime.h>
#include <math.h>

#define T_SEQ 512
#define BATCH 256
#define HID   512
#define IN0   64
#define K1    1024           /* L1: 512 h0 + 512 h1 */
#define K0    576            /* L0: 64 x + 512 h0   */
#define NWG   128
#define NTHR  1024
#define LDS_DYN 131072

typedef __bf16 b16x8 __attribute__((ext_vector_type(8)));
typedef float  f32x4 __attribute__((ext_vector_type(4)));

__device__ __forceinline__ float sigm(float x)   { return 1.0f / (1.0f + __expf(-x)); }
__device__ __forceinline__ float tanh_f(float x) { return 2.0f / (1.0f + __expf(-2.0f * x)) - 1.0f; }

__device__ __forceinline__ f32x4 mfma16(b16x8 a, b16x8 b, f32x4 c) {
  return __builtin_amdgcn_mfma_f32_16x16x32_bf16(a, b, c, 0, 0, 0);
}

// write-through stores to the coherence point (no dirty L2 anywhere)
__device__ __forceinline__ void store_short_wt(const __bf16* p, unsigned v) {
  asm volatile("global_store_short %0, %1, off sc0 sc1"
               :: "v"((const void*)p), "v"(v) : "memory");
}
__device__ __forceinline__ void store_dword_wt(const unsigned* p, unsigned v) {
  asm volatile("global_store_dword %0, %1, off sc0 sc1"
               :: "v"((const void*)p), "v"(v) : "memory");
}

// ---------- prep: split W into LDS-order layout ----------
// rows permuted r = hcol*4 + gate; k-concat ih|hh.
// out layout: [slice s=r>>4][kc=k>>3][row16=r&15][ke=k&7]  (16-B chunks contiguous)
__global__ void k_split_w(const float* __restrict__ Wih, const float* __restrict__ Whh,
                          const float* __restrict__ bih, const float* __restrict__ bhh,
                          __bf16* __restrict__ whi, __bf16* __restrict__ wlo,
                          float* __restrict__ bias, int Kin) {
  int K = Kin + HID;
  long idx = (long)blockIdx.x * 256 + threadIdx.x;
  long total = 2048L * K;
  if (idx < total) {
    int k = (int)(idx % K);
    int r = (int)(idx / K);
    int gate = r & 3, hcol = r >> 2;
    int row = gate * HID + hcol;
    float v = (k < Kin) ? Wih[(long)row * Kin + k] : Whh[(long)row * HID + (k - Kin)];
    __bf16 h = (__bf16)v;
    long o = (long)(r >> 4) * 16 * K + (long)(k >> 3) * 128 + (r & 15) * 8 + (k & 7);
    whi[o] = h;
    wlo[o] = (__bf16)(v - (float)h);
  }
  if (idx < 2048) {
    int r = (int)idx;
    int gate = r & 3, hcol = r >> 2;
    int row = gate * HID + hcol;
    bias[r] = bih[row] + bhh[row];
  }
}

// ---------- prep: x[B][T][I] -> split bf16 [T][B][I] ----------
__global__ void k_split_x(const float* __restrict__ x,
                          __bf16* __restrict__ xhi, __bf16* __restrict__ xlo) {
  int idx = blockIdx.x * 256 + threadIdx.x;   // dst index, [t][b][i]
  int i = idx & 63;
  int b = (idx >> 6) & 255;
  int t = idx >> 14;
  float v = x[((size_t)b * T_SEQ + t) * IN0 + i];
  __bf16 h = (__bf16)v;
  xhi[idx] = h;
  xlo[idx] = (__bf16)(v - (float)h);
}

// ---------- two-level tree grid barrier + mirrored release lines ----------
// bar[0]          : top counter; epoch e complete when top hits 8*e
// bar[32+g*32]    : per-group arrival counter (g = wg&7, 16 members each)
// bar[512+g*32]   : per-group release mirror (polled line, one per group)
// All counters monotonic -> no reset race. Data release ordering comes from
// callers' s_waitcnt vmcnt(0) after write-through stores; acquire fence
// (buffer_inv only) makes peers' WT stores visible after release.
__device__ __forceinline__ void grid_barrier(unsigned* bar, unsigned epoch) {
  __syncthreads();
  if (threadIdx.x == 0) {
    const unsigned g = blockIdx.x & 7;
    unsigned a = __hip_atomic_fetch_add(&bar[32 + g * 32], 1u,
                                        __ATOMIC_RELAXED, __HIP_MEMORY_SCOPE_AGENT);
    if (a == epoch * 16u - 1u) {   // 16th arrival of this epoch in this group
      unsigned t = __hip_atomic_fetch_add(&bar[0], 1u,
                                          __ATOMIC_RELAXED, __HIP_MEMORY_SCOPE_AGENT);
      if (t == epoch * 8u - 1u) {  // last group in: broadcast release
        #pragma unroll
        for (int gg = 0; gg < 8; ++gg)
          store_dword_wt(&bar[512 + gg * 32], epoch);
      }
    }
    while ((int)(__hip_atomic_load(&bar[512 + g * 32],
                                   __ATOMIC_RELAXED, __HIP_MEMORY_SCOPE_AGENT) - epoch) < 0)
      __builtin_amdgcn_s_sleep(4);
    __builtin_amdgcn_fence(__ATOMIC_ACQUIRE, "agent");   // buffer_inv only
  }
  __syncthreads();
}

// ---------- persistent MFMA LSTM ----------
// 128 wgs x 1024 thr (16 waves, 4/SIMD). wg<64: layer1 rows wg*32..+31;
// wg>=64: layer0 rows (wg-64)*32..+31.
// Wave wv: row-slice sl = wv&1 (16 rows), batch block (wv>>1)*32 -> acc[2], c[2].
// Weights (split hi/lo) for the wg's 32 rows live in 128 KB dynamic LDS, loaded ONCE.
// D layout: col=lane&15 (batch), row=(lane>>4)*4+reg. Rows permuted hcol*4+gate =>
// lane's 4 acc regs = i,f,g,o of one (hcol,batch): cell update lane-local, c in regs.
// Activations in1{hi,lo}[2][256][1024]: cols 0..511 = h0, 512..1023 = h1, k-major.
__global__ __launch_bounds__(NTHR, 1) void k_lstm(
    const __bf16* __restrict__ xhi, const __bf16* __restrict__ xlo,
    const __bf16* __restrict__ w0hi, const __bf16* __restrict__ w0lo, const float* __restrict__ bias0,
    const __bf16* __restrict__ w1hi, const __bf16* __restrict__ w1lo, const float* __restrict__ bias1,
    __bf16* __restrict__ in1hi, __bf16* __restrict__ in1lo,
    const float* __restrict__ fcw, const float* __restrict__ fcb,
    float* __restrict__ out, unsigned* __restrict__ bar)
{
  extern __shared__ __align__(16) __bf16 ldsA[];   // [hi 32*KW | lo 32*KW]

  const int tid  = threadIdx.x;
  const int lane = tid & 63;
  const int wv   = __builtin_amdgcn_readfirstlane(tid >> 6);   // 0..15
  const int wg   = blockIdx.x;
  const int layer1 = (wg < 64) ? 1 : 0;
  const int lw   = wg & 63;
  const int sl   = wv & 1;             // row-slice (16 rows) within the wg's 32
  const int bbase = (wv >> 1) * 32;    // batch block
  const int lr = lane & 15;            // A-row16 / B-batch / D-col offset
  const int lg = lane >> 4;            // k-subgroup (A/B), row-subgroup (D)
  const int KW = layer1 ? K1 : K0;

  // ---- one-time: load this wg's 32-row weight slice into LDS ----
  {
    const b16x8* gh = reinterpret_cast<const b16x8*>((layer1 ? w1hi : w0hi) + (size_t)lw * 32 * KW);
    const b16x8* gl = reinterpret_cast<const b16x8*>((layer1 ? w1lo : w0lo) + (size_t)lw * 32 * KW);
    b16x8* lh = reinterpret_cast<b16x8*>(ldsA);
    b16x8* ll = reinterpret_cast<b16x8*>(ldsA + 32 * KW);
    const int nch = 4 * KW;            // 32*KW/8 chunks of 16 B
    for (int ch = tid; ch < nch; ch += NTHR) { lh[ch] = gh[ch]; ll[ch] = gl[ch]; }
  }
  __syncthreads();

  const int hc = lw * 8 + sl * 4 + lg;   // hidden column this lane owns
  const float4 b4 = *reinterpret_cast<const float4*>((layer1 ? bias1 : bias0) + hc * 4);
  const b16x8* Ah = reinterpret_cast<const b16x8*>(ldsA) + (size_t)sl * 2 * KW;
  const b16x8* Al = reinterpret_cast<const b16x8*>(ldsA + 32 * KW) + (size_t)sl * 2 * KW;

  float c[2] = {0.f, 0.f};

  #pragma unroll 1
  for (int n = 0; n <= T_SEQ; ++n) {
    const int pr = (n + 1) & 1;   // read parity
    const int pw = n & 1;         // write parity
    const bool active = layer1 ? (n >= 1) : (n < T_SEQ);
    if (active) {
      f32x4 acc[2];
      #pragma unroll
      for (int st = 0; st < 2; ++st) { acc[st][0]=b4.x; acc[st][1]=b4.y; acc[st][2]=b4.z; acc[st][3]=b4.w; }

      const __bf16* Bh = in1hi + ((size_t)pr * BATCH + bbase) * K1 + lg * 8;
      const __bf16* Bl = in1lo + ((size_t)pr * BATCH + bbase) * K1 + lg * 8;

      if (layer1) {
        #pragma unroll 4
        for (int ks = 0; ks < 32; ++ks) {
          b16x8 ah = Ah[(ks * 4 + lg) * 16 + lr];
          b16x8 al = Al[(ks * 4 + lg) * 16 + lr];
          #pragma unroll
          for (int st = 0; st < 2; ++st) {
            const size_t bo = (size_t)(st * 16 + lr) * K1 + ks * 32;
            b16x8 bh = *reinterpret_cast<const b16x8*>(Bh + bo);
            b16x8 bl = *reinterpret_cast<const b16x8*>(Bl + bo);
            acc[st] = mfma16(ah, bh, acc[st]);
            acc[st] = mfma16(ah, bl, acc[st]);
            acc[st] = mfma16(al, bh, acc[st]);
          }
        }
      } else {
        const __bf16* Xh = xhi + ((size_t)n * BATCH + bbase) * IN0 + lg * 8;
        const __bf16* Xl = xlo + ((size_t)n * BATCH + bbase) * IN0 + lg * 8;
        #pragma unroll
        for (int ks = 0; ks < 2; ++ks) {            // x part: k 0..63
          b16x8 ah = Ah[(ks * 4 + lg) * 16 + lr];
          b16x8 al = Al[(ks * 4 + lg) * 16 + lr];
          #pragma unroll
          for (int st = 0; st < 2; ++st) {
            const size_t bo = (size_t)(st * 16 + lr) * IN0 + ks * 32;
            b16x8 bh = *reinterpret_cast<const b16x8*>(Xh + bo);
            b16x8 bl = *reinterpret_cast<const b16x8*>(Xl + bo);
            acc[st] = mfma16(ah, bh, acc[st]);
            acc[st] = mfma16(ah, bl, acc[st]);
            acc[st] = mfma16(al, bh, acc[st]);
          }
        }
        #pragma unroll 4
        for (int ks = 0; ks < 16; ++ks) {           // h0 part: weight k 64.., in1 cols 0..511
          b16x8 ah = Ah[((8 + ks * 4) + lg) * 16 + lr];
          b16x8 al = Al[((8 + ks * 4) + lg) * 16 + lr];
          #pragma unroll
          for (int st = 0; st < 2; ++st) {
            const size_t bo = (size_t)(st * 16 + lr) * K1 + ks * 32;
            b16x8 bh = *reinterpret_cast<const b16x8*>(Bh + bo);
            b16x8 bl = *reinterpret_cast<const b16x8*>(Bl + bo);
            acc[st] = mfma16(ah, bh, acc[st]);
            acc[st] = mfma16(ah, bl, acc[st]);
            acc[st] = mfma16(al, bh, acc[st]);
          }
        }
      }

      // ---- lane-local cell update; write-through split-bf16 h stores ----
      const int colbase = layer1 ? (512 + hc) : hc;
      #pragma unroll
      for (int st = 0; st < 2; ++st) {
        float i_ = sigm(acc[st][0]);
        float f_ = sigm(acc[st][1]);
        float g_ = tanh_f(acc[st][2]);
        float o_ = sigm(acc[st][3]);
        c[st] = fmaf(f_, c[st], i_ * g_);
        float hv = o_ * tanh_f(c[st]);
        __bf16 hh = (__bf16)hv;
        __bf16 hl = (__bf16)(hv - (float)hh);
        const int b = bbase + st * 16 + lr;
        const size_t idx = ((size_t)pw * BATCH + b) * K1 + colbase;
        store_short_wt(in1hi + idx, (unsigned)__builtin_bit_cast(unsigned short, hh));
        store_short_wt(in1lo + idx, (unsigned)__builtin_bit_cast(unsigned short, hl));
      }
      asm volatile("s_waitcnt vmcnt(0)" ::: "memory");  // release: stores at coherence point
    }
    grid_barrier(bar, (unsigned)(n + 1));
  }

  // ---- final FC on h1[511] (written at iter 512, parity 0), cols 512..1023 ----
  if (wg == 0 && tid < BATCH) {
    const __bf16* rh = in1hi + (size_t)tid * K1 + 512;
    const __bf16* rl = in1lo + (size_t)tid * K1 + 512;
    float acc = 0.f;
    #pragma unroll 8
    for (int k = 0; k < HID; ++k)
      acc = fmaf((float)rh[k] + (float)rl[k], fcw[k], acc);
    out[tid] = acc + fcb[0];
  }
}

// ---------- host ----------
extern "C" void kernel_launch(void* const* d_in, const int* in_sizes, int n_in,
                              void* d_out, int out_size, void* d_ws, size_t ws_size,
                              hipStream_t stream) {
  const float* x    = (const float*)d_in[0];
  const float* Wih0 = (const float*)d_in[1];
  const float* Whh0 = (const float*)d_in[2];
  const float* bih0 = (const float*)d_in[3];
  const float* bhh0 = (const float*)d_in[4];
  const float* Wih1 = (const float*)d_in[5];
  const float* Whh1 = (const float*)d_in[6];
  const float* bih1 = (const float*)d_in[7];
  const float* bhh1 = (const float*)d_in[8];
  const float* fcw  = (const float*)d_in[9];
  const float* fcb  = (const float*)d_in[10];

  char* ws = (char*)d_ws;
  size_t off = 0;
  auto alloc = [&](size_t bytes) -> char* {
    char* pp = ws + off;
    off = (off + bytes + 1023) & ~(size_t)1023;
    return pp;
  };
  unsigned* bar  = (unsigned*)alloc(4096);
  __bf16* xhi  = (__bf16*)alloc((size_t)T_SEQ * BATCH * IN0 * 2);   // 16.8 MB
  __bf16* xlo  = (__bf16*)alloc((size_t)T_SEQ * BATCH * IN0 * 2);
  __bf16* w0hi = (__bf16*)alloc((size_t)2048 * K0 * 2);             // 2.36 MB
  __bf16* w0lo = (__bf16*)alloc((size_t)2048 * K0 * 2);
  __bf16* w1hi = (__bf16*)alloc((size_t)2048 * K1 * 2);             // 4.2 MB
  __bf16* w1lo = (__bf16*)alloc((size_t)2048 * K1 * 2);
  float*  bias0 = (float*)alloc(2048 * 4);
  float*  bias1 = (float*)alloc(2048 * 4);
  __bf16* in1hi = (__bf16*)alloc((size_t)2 * BATCH * K1 * 2);       // 1 MB
  __bf16* in1lo = (__bf16*)alloc((size_t)2 * BATCH * K1 * 2);

  static bool attr_done = false;
  if (!attr_done) {
    (void)hipFuncSetAttribute(reinterpret_cast<const void*>(k_lstm),
                              hipFuncAttributeMaxDynamicSharedMemorySize, LDS_DYN);
    attr_done = true;
  }

  (void)hipMemsetAsync(bar, 0, 4096, stream);
  (void)hipMemsetAsync(in1hi, 0, (size_t)2 * BATCH * K1 * 2, stream);
  (void)hipMemsetAsync(in1lo, 0, (size_t)2 * BATCH * K1 * 2, stream);
  k_split_x<<<(T_SEQ * BATCH * IN0) / 256, 256, 0, stream>>>(x, xhi, xlo);
  k_split_w<<<(int)((2048L * K0 + 255) / 256), 256, 0, stream>>>(Wih0, Whh0, bih0, bhh0, w0hi, w0lo, bias0, IN0);
  k_split_w<<<(int)((2048L * K1 + 255) / 256), 256, 0, stream>>>(Wih1, Whh1, bih1, bhh1, w1hi, w1lo, bias1, HID);
  k_lstm<<<NWG, NTHR, LDS_DYN, stream>>>(xhi, xlo, w0hi, w0lo, bias0, w1hi, w1lo, bias1,
                                         in1hi, in1lo, fcw, fcb, (float*)d_out, bar);
}

// Round 9
// 16617.938 us; speedup vs baseline: 1.8668x; 1.8668x over previous
//
#include <hip/hip_runtime.h>
#include <math.h>

#define T_SEQ 512
#define BATCH 256
#define HID   512
#define IN0   64
#define K1    1024           /* L1: 512 h0 + 512 h1 */
#define K0    576            /* L0: 64 x + 512 h0   */
#define NWG   256
#define NTHR  512
#define LDS_DYN 131072

typedef __bf16 b16x8 __attribute__((ext_vector_type(8)));
typedef float  f32x4 __attribute__((ext_vector_type(4)));

__device__ __forceinline__ float sigm(float x)   { return 1.0f / (1.0f + __expf(-x)); }
__device__ __forceinline__ float tanh_f(float x) { return 2.0f / (1.0f + __expf(-2.0f * x)) - 1.0f; }

__device__ __forceinline__ f32x4 mfma16(b16x8 a, b16x8 b, f32x4 c) {
  return __builtin_amdgcn_mfma_f32_16x16x32_bf16(a, b, c, 0, 0, 0);
}

// write-through stores to the coherence point (no dirty L2 anywhere)
__device__ __forceinline__ void store_short_wt(const __bf16* p, unsigned v) {
  asm volatile("global_store_short %0, %1, off sc0 sc1"
               :: "v"((const void*)p), "v"(v) : "memory");
}
__device__ __forceinline__ void store_dword_wt(const unsigned* p, unsigned v) {
  asm volatile("global_store_dword %0, %1, off sc0 sc1"
               :: "v"((const void*)p), "v"(v) : "memory");
}

// ---------- prep: split W into LDS-order layout ----------
// rows permuted r = hcol*4 + gate; k-concat ih|hh.
// out layout: [slice s=r>>4][kc=k>>3][row16=r&15][ke=k&7]  (16-B chunks contiguous)
__global__ void k_split_w(const float* __restrict__ Wih, const float* __restrict__ Whh,
                          const float* __restrict__ bih, const float* __restrict__ bhh,
                          __bf16* __restrict__ whi, __bf16* __restrict__ wlo,
                          float* __restrict__ bias, int Kin) {
  int K = Kin + HID;
  long idx = (long)blockIdx.x * 256 + threadIdx.x;
  long total = 2048L * K;
  if (idx < total) {
    int k = (int)(idx % K);
    int r = (int)(idx / K);
    int gate = r & 3, hcol = r >> 2;
    int row = gate * HID + hcol;
    float v = (k < Kin) ? Wih[(long)row * Kin + k] : Whh[(long)row * HID + (k - Kin)];
    __bf16 h = (__bf16)v;
    long o = (long)(r >> 4) * 16 * K + (long)(k >> 3) * 128 + (r & 15) * 8 + (k & 7);
    whi[o] = h;
    wlo[o] = (__bf16)(v - (float)h);
  }
  if (idx < 2048) {
    int r = (int)idx;
    int gate = r & 3, hcol = r >> 2;
    int row = gate * HID + hcol;
    bias[r] = bih[row] + bhh[row];
  }
}

// ---------- prep: x[B][T][I] -> split bf16 [T][B][I] ----------
__global__ void k_split_x(const float* __restrict__ x,
                          __bf16* __restrict__ xhi, __bf16* __restrict__ xlo) {
  int idx = blockIdx.x * 256 + threadIdx.x;   // dst index, [t][b][i]
  int i = idx & 63;
  int b = (idx >> 6) & 255;
  int t = idx >> 14;
  float v = x[((size_t)b * T_SEQ + t) * IN0 + i];
  __bf16 h = (__bf16)v;
  xhi[idx] = h;
  xlo[idx] = (__bf16)(v - (float)h);
}

// ---------- two-level tree grid barrier + mirrored release lines ----------
// bar[0]          : top counter; epoch e complete when top hits 8*e
// bar[32+g*32]    : per-group arrival counter (g = wg&7, 32 members each)
// bar[512+g*32]   : per-group release mirror (polled line, one per group)
// All counters monotonic -> no reset race. Data release ordering comes from
// callers' s_waitcnt vmcnt(0) after write-through stores; acquire fence
// (buffer_inv only) makes peers' WT stores visible after release.
__device__ __forceinline__ void grid_barrier(unsigned* bar, unsigned epoch) {
  __syncthreads();
  if (threadIdx.x == 0) {
    const unsigned g = blockIdx.x & 7;
    unsigned a = __hip_atomic_fetch_add(&bar[32 + g * 32], 1u,
                                        __ATOMIC_RELAXED, __HIP_MEMORY_SCOPE_AGENT);
    if (a == epoch * 32u - 1u) {   // 32nd arrival of this epoch in this group
      unsigned t = __hip_atomic_fetch_add(&bar[0], 1u,
                                          __ATOMIC_RELAXED, __HIP_MEMORY_SCOPE_AGENT);
      if (t == epoch * 8u - 1u) {  // last group in: broadcast release
        #pragma unroll
        for (int gg = 0; gg < 8; ++gg)
          store_dword_wt(&bar[512 + gg * 32], epoch);
      }
    }
    while ((int)(__hip_atomic_load(&bar[512 + g * 32],
                                   __ATOMIC_RELAXED, __HIP_MEMORY_SCOPE_AGENT) - epoch) < 0)
      __builtin_amdgcn_s_sleep(4);
    __builtin_amdgcn_fence(__ATOMIC_ACQUIRE, "agent");   // buffer_inv only
  }
  __syncthreads();
}

// ---------- B-stream GEMM core with double-buffered register prefetch ----------
// NCH chunks of CK=4 k-steps; per chunk: 16 global b16x8 loads in flight while
// MFMAing the other buffer. All buffer indices compile-time (full unroll).
template<int NCH>
__device__ __forceinline__ void bstream(const __bf16* __restrict__ Bh,
                                        const __bf16* __restrict__ Bl,
                                        const b16x8* __restrict__ Ah,
                                        const b16x8* __restrict__ Al,
                                        int aoff, int lr, int lg, f32x4* acc)
{
  constexpr int CK = 4;
  b16x8 bufA[CK][2][2], bufB[CK][2][2];

  auto load = [&](b16x8 (&buf)[CK][2][2], int ksb) {
    #pragma unroll
    for (int kk = 0; kk < CK; ++kk) {
      #pragma unroll
      for (int st = 0; st < 2; ++st) {
        const size_t bo = (size_t)(st * 16 + lr) * K1 + (size_t)(ksb + kk) * 32;
        buf[kk][st][0] = *reinterpret_cast<const b16x8*>(Bh + bo);
        buf[kk][st][1] = *reinterpret_cast<const b16x8*>(Bl + bo);
      }
    }
  };
  auto mm = [&](b16x8 (&buf)[CK][2][2], int ksb) {
    #pragma unroll
    for (int kk = 0; kk < CK; ++kk) {
      const int ac = (aoff + (ksb + kk) * 4 + lg) * 16 + lr;
      b16x8 ah = Ah[ac];
      b16x8 al = Al[ac];
      #pragma unroll
      for (int st = 0; st < 2; ++st) {
        acc[st] = mfma16(ah, buf[kk][st][0], acc[st]);
        acc[st] = mfma16(ah, buf[kk][st][1], acc[st]);
        acc[st] = mfma16(al, buf[kk][st][0], acc[st]);
      }
    }
  };

  load(bufA, 0);
  #pragma unroll 1
  for (int cb = 0; cb < NCH; cb += 2) {
    if (cb + 1 < NCH) load(bufB, (cb + 1) * CK);
    mm(bufA, cb * CK);
    if (cb + 2 < NCH) load(bufA, (cb + 2) * CK);
    if (cb + 1 < NCH) mm(bufB, (cb + 1) * CK);
  }
}

// ---------- persistent MFMA LSTM ----------
// 256 wgs x 512 thr (8 waves, 2/SIMD). wg<128: layer1, rg=(wg&127)>>1, bg=wg&1;
// wg>=128: layer0 same on (wg-128). wg tile = 32 rows x 128 batch.
// Wave wv: sl=wv&1 (16-row slice), bb=wv>>1 (32-batch block) -> acc[2], c[2].
// Weights (split hi/lo) for the wg's 32 rows in 128 KB dynamic LDS, loaded ONCE.
// D layout: col=lane&15 (batch), row=(lane>>4)*4+reg. Rows permuted hcol*4+gate =>
// lane's 4 acc regs = i,f,g,o of one (hcol,batch): cell update lane-local, c in regs.
// Activations in1{hi,lo}[2][256][1024]: cols 0..511 = h0, 512..1023 = h1, k-major.
__global__ __launch_bounds__(NTHR, 2) void k_lstm(
    const __bf16* __restrict__ xhi, const __bf16* __restrict__ xlo,
    const __bf16* __restrict__ w0hi, const __bf16* __restrict__ w0lo, const float* __restrict__ bias0,
    const __bf16* __restrict__ w1hi, const __bf16* __restrict__ w1lo, const float* __restrict__ bias1,
    __bf16* __restrict__ in1hi, __bf16* __restrict__ in1lo,
    const float* __restrict__ fcw, const float* __restrict__ fcb,
    float* __restrict__ out, unsigned* __restrict__ bar)
{
  extern __shared__ __align__(16) __bf16 ldsA[];   // [hi 32*KW | lo 32*KW]

  const int tid  = threadIdx.x;
  const int lane = tid & 63;
  const int wv   = __builtin_amdgcn_readfirstlane(tid >> 6);   // 0..7
  const int wg   = blockIdx.x;
  const int layer1 = (wg < 128) ? 1 : 0;
  const int lw   = wg & 127;
  const int rg   = lw >> 1;            // 0..63 row-group (32 rows)
  const int bg   = lw & 1;             // 0..1 batch-group (128 batch)
  const int sl   = wv & 1;             // 16-row slice within the 32
  const int bb   = wv >> 1;            // 0..3 batch block (32)
  const int bbase = bg * 128 + bb * 32;
  const int lr = lane & 15;            // A-row16 / B-batch / D-col offset
  const int lg = lane >> 4;            // k-subgroup (A/B), row-subgroup (D)
  const int KW = layer1 ? K1 : K0;

  // ---- one-time: load this wg's 32-row weight slice into LDS ----
  {
    const b16x8* gh = reinterpret_cast<const b16x8*>((layer1 ? w1hi : w0hi) + (size_t)rg * 32 * KW);
    const b16x8* gl = reinterpret_cast<const b16x8*>((layer1 ? w1lo : w0lo) + (size_t)rg * 32 * KW);
    b16x8* lh = reinterpret_cast<b16x8*>(ldsA);
    b16x8* ll = reinterpret_cast<b16x8*>(ldsA + 32 * KW);
    const int nch = 4 * KW;            // 32*KW/8 chunks of 16 B
    for (int ch = tid; ch < nch; ch += NTHR) { lh[ch] = gh[ch]; ll[ch] = gl[ch]; }
  }
  __syncthreads();

  const int hc = rg * 8 + sl * 4 + lg;   // hidden column this lane owns
  const float4 b4 = *reinterpret_cast<const float4*>((layer1 ? bias1 : bias0) + hc * 4);
  const b16x8* Ah = reinterpret_cast<const b16x8*>(ldsA) + (size_t)sl * 2 * KW;
  const b16x8* Al = reinterpret_cast<const b16x8*>(ldsA + 32 * KW) + (size_t)sl * 2 * KW;

  float c[2] = {0.f, 0.f};

  #pragma unroll 1
  for (int n = 0; n <= T_SEQ; ++n) {
    const int pr = (n + 1) & 1;   // read parity
    const int pw = n & 1;         // write parity
    const bool active = layer1 ? (n >= 1) : (n < T_SEQ);
    if (active) {
      f32x4 acc[2];
      #pragma unroll
      for (int st = 0; st < 2; ++st) { acc[st][0]=b4.x; acc[st][1]=b4.y; acc[st][2]=b4.z; acc[st][3]=b4.w; }

      const __bf16* Bh = in1hi + ((size_t)pr * BATCH + bbase) * K1 + lg * 8;
      const __bf16* Bl = in1lo + ((size_t)pr * BATCH + bbase) * K1 + lg * 8;

      if (layer1) {
        bstream<8>(Bh, Bl, Ah, Al, 0, lr, lg, acc);
      } else {
        const __bf16* Xh = xhi + ((size_t)n * BATCH + bbase) * IN0 + lg * 8;
        const __bf16* Xl = xlo + ((size_t)n * BATCH + bbase) * IN0 + lg * 8;
        #pragma unroll
        for (int ks = 0; ks < 2; ++ks) {            // x part: k 0..63
          b16x8 ah = Ah[(ks * 4 + lg) * 16 + lr];
          b16x8 al = Al[(ks * 4 + lg) * 16 + lr];
          #pragma unroll
          for (int st = 0; st < 2; ++st) {
            const size_t bo = (size_t)(st * 16 + lr) * IN0 + ks * 32;
            b16x8 bh = *reinterpret_cast<const b16x8*>(Xh + bo);
            b16x8 bl = *reinterpret_cast<const b16x8*>(Xl + bo);
            acc[st] = mfma16(ah, bh, acc[st]);
            acc[st] = mfma16(ah, bl, acc[st]);
            acc[st] = mfma16(al, bh, acc[st]);
          }
        }
        bstream<4>(Bh, Bl, Ah, Al, 8, lr, lg, acc);  // h0 part: weight k 64..575
      }

      // ---- lane-local cell update; write-through split-bf16 h stores ----
      const int colbase = layer1 ? (512 + hc) : hc;
      #pragma unroll
      for (int st = 0; st < 2; ++st) {
        float i_ = sigm(acc[st][0]);
        float f_ = sigm(acc[st][1]);
        float g_ = tanh_f(acc[st][2]);
        float o_ = sigm(acc[st][3]);
        c[st] = fmaf(f_, c[st], i_ * g_);
        float hv = o_ * tanh_f(c[st]);
        __bf16 hh = (__bf16)hv;
        __bf16 hl = (__bf16)(hv - (float)hh);
        const int b = bbase + st * 16 + lr;
        const size_t idx = ((size_t)pw * BATCH + b) * K1 + colbase;
        store_short_wt(in1hi + idx, (unsigned)__builtin_bit_cast(unsigned short, hh));
        store_short_wt(in1lo + idx, (unsigned)__builtin_bit_cast(unsigned short, hl));
      }
      asm volatile("s_waitcnt vmcnt(0)" ::: "memory");  // release: stores at coherence point
    }
    grid_barrier(bar, (unsigned)(n + 1));
  }

  // ---- final FC on h1[511] (written at iter 512, parity 0), cols 512..1023 ----
  if (wg == 0 && tid < BATCH) {
    const __bf16* rh = in1hi + (size_t)tid * K1 + 512;
    const __bf16* rl = in1lo + (size_t)tid * K1 + 512;
    float acc = 0.f;
    #pragma unroll 8
    for (int k = 0; k < HID; ++k)
      acc = fmaf((float)rh[k] + (float)rl[k], fcw[k], acc);
    out[tid] = acc + fcb[0];
  }
}

// ---------- host ----------
extern "C" void kernel_launch(void* const* d_in, const int* in_sizes, int n_in,
                              void* d_out, int out_size, void* d_ws, size_t ws_size,
                              hipStream_t stream) {
  const float* x    = (const float*)d_in[0];
  const float* Wih0 = (const float*)d_in[1];
  const float* Whh0 = (const float*)d_in[2];
  const float* bih0 = (const float*)d_in[3];
  const float* bhh0 = (const float*)d_in[4];
  const float* Wih1 = (const float*)d_in[5];
  const float* Whh1 = (const float*)d_in[6];
  const float* bih1 = (const float*)d_in[7];
  const float* bhh1 = (const float*)d_in[8];
  const float* fcw  = (const float*)d_in[9];
  const float* fcb  = (const float*)d_in[10];

  char* ws = (char*)d_ws;
  size_t off = 0;
  auto alloc = [&](size_t bytes) -> char* {
    char* pp = ws + off;
    off = (off + bytes + 1023) & ~(size_t)1023;
    return pp;
  };
  unsigned* bar  = (unsigned*)alloc(4096);
  __bf16* xhi  = (__bf16*)alloc((size_t)T_SEQ * BATCH * IN0 * 2);   // 16.8 MB
  __bf16* xlo  = (__bf16*)alloc((size_t)T_SEQ * BATCH * IN0 * 2);
  __bf16* w0hi = (__bf16*)alloc((size_t)2048 * K0 * 2);             // 2.36 MB
  __bf16* w0lo = (__bf16*)alloc((size_t)2048 * K0 * 2);
  __bf16* w1hi = (__bf16*)alloc((size_t)2048 * K1 * 2);             // 4.2 MB
  __bf16* w1lo = (__bf16*)alloc((size_t)2048 * K1 * 2);
  float*  bias0 = (float*)alloc(2048 * 4);
  float*  bias1 = (float*)alloc(2048 * 4);
  __bf16* in1hi = (__bf16*)alloc((size_t)2 * BATCH * K1 * 2);       // 1 MB
  __bf16* in1lo = (__bf16*)alloc((size_t)2 * BATCH * K1 * 2);

  static bool attr_done = false;
  if (!attr_done) {
    (void)hipFuncSetAttribute(reinterpret_cast<const void*>(k_lstm),
                              hipFuncAttributeMaxDynamicSharedMemorySize, LDS_DYN);
    attr_done = true;
  }

  (void)hipMemsetAsync(bar, 0, 4096, stream);
  (void)hipMemsetAsync(in1hi, 0, (size_t)2 * BATCH * K1 * 2, stream);
  (void)hipMemsetAsync(in1lo, 0, (size_t)2 * BATCH * K1 * 2, stream);
  k_split_x<<<(T_SEQ * BATCH * IN0) / 256, 256, 0, stream>>>(x, xhi, xlo);
  k_split_w<<<(int)((2048L * K0 + 255) / 256), 256, 0, stream>>>(Wih0, Whh0, bih0, bhh0, w0hi, w0lo, bias0, IN0);
  k_split_w<<<(int)((2048L * K1 + 255) / 256), 256, 0, stream>>>(Wih1, Whh1, bih1, bhh1, w1hi, w1lo, bias1, HID);
  k_lstm<<<NWG, NTHR, LDS_DYN, stream>>>(xhi, xlo, w0hi, w0lo, bias0, w1hi, w1lo, bias1,
                                         in1hi, in1lo, fcw, fcb, (float*)d_out, bar);
}

// Round 10
// 9703.854 us; speedup vs baseline: 3.1969x; 1.7125x over previous
//
#include <hip/hip_runtime.h>
#include <math.h>

#define T_SEQ 512
#define BATCH 256
#define HID   512
#define IN0   64
#define K1    1024           /* L1: 512 h0 + 512 h1 */
#define K0    576            /* L0: 64 x + 512 h0   */
#define NWG   256
#define NTHR  512
#define LDS_DYN 131072

typedef __bf16 b16x8 __attribute__((ext_vector_type(8)));
typedef float  f32x4 __attribute__((ext_vector_type(4)));

__device__ __forceinline__ float sigm(float x)   { return 1.0f / (1.0f + __expf(-x)); }
__device__ __forceinline__ float tanh_f(float x) { return 2.0f / (1.0f + __expf(-2.0f * x)) - 1.0f; }

__device__ __forceinline__ f32x4 mfma16(b16x8 a, b16x8 b, f32x4 c) {
  return __builtin_amdgcn_mfma_f32_16x16x32_bf16(a, b, c, 0, 0, 0);
}

// write-through stores to the coherence point (no dirty L2 anywhere)
__device__ __forceinline__ void store_short_wt(const __bf16* p, unsigned v) {
  asm volatile("global_store_short %0, %1, off sc0 sc1"
               :: "v"((const void*)p), "v"(v) : "memory");
}
__device__ __forceinline__ void store_dword_wt(const unsigned* p, unsigned v) {
  asm volatile("global_store_dword %0, %1, off sc0 sc1"
               :: "v"((const void*)p), "v"(v) : "memory");
}

// ---------- prep: split W into LDS-order layout ----------
// rows permuted r = hcol*4 + gate; k-concat ih|hh.
// out layout: [slice s=r>>4][kc=k>>3][row16=r&15][ke=k&7]  (16-B chunks contiguous)
__global__ void k_split_w(const float* __restrict__ Wih, const float* __restrict__ Whh,
                          const float* __restrict__ bih, const float* __restrict__ bhh,
                          __bf16* __restrict__ whi, __bf16* __restrict__ wlo,
                          float* __restrict__ bias, int Kin) {
  int K = Kin + HID;
  long idx = (long)blockIdx.x * 256 + threadIdx.x;
  long total = 2048L * K;
  if (idx < total) {
    int k = (int)(idx % K);
    int r = (int)(idx / K);
    int gate = r & 3, hcol = r >> 2;
    int row = gate * HID + hcol;
    float v = (k < Kin) ? Wih[(long)row * Kin + k] : Whh[(long)row * HID + (k - Kin)];
    __bf16 h = (__bf16)v;
    long o = (long)(r >> 4) * 16 * K + (long)(k >> 3) * 128 + (r & 15) * 8 + (k & 7);
    whi[o] = h;
    wlo[o] = (__bf16)(v - (float)h);
  }
  if (idx < 2048) {
    int r = (int)idx;
    int gate = r & 3, hcol = r >> 2;
    int row = gate * HID + hcol;
    bias[r] = bih[row] + bhh[row];
  }
}

// ---------- prep: x[B][T][I] -> split bf16 [T][B][I] ----------
__global__ void k_split_x(const float* __restrict__ x,
                          __bf16* __restrict__ xhi, __bf16* __restrict__ xlo) {
  int idx = blockIdx.x * 256 + threadIdx.x;   // dst index, [t][b][i]
  int i = idx & 63;
  int b = (idx >> 6) & 255;
  int t = idx >> 14;
  float v = x[((size_t)b * T_SEQ + t) * IN0 + i];
  __bf16 h = (__bf16)v;
  xhi[idx] = h;
  xlo[idx] = (__bf16)(v - (float)h);
}

// ---------- two-level tree grid barrier + mirrored release lines ----------
// bar[0]          : top counter; epoch e complete when top hits 8*e
// bar[32+g*32]    : per-group arrival counter (g = wg&7, 32 members each)
// bar[512+g*32]   : per-group release mirror (polled line, one per group)
// All counters monotonic -> no reset race. Data release ordering comes from
// callers' s_waitcnt vmcnt(0) after write-through stores; acquire fence
// (buffer_inv only) makes peers' WT stores visible after release.
__device__ __forceinline__ void grid_barrier(unsigned* bar, unsigned epoch) {
  __syncthreads();
  if (threadIdx.x == 0) {
    const unsigned g = blockIdx.x & 7;
    unsigned a = __hip_atomic_fetch_add(&bar[32 + g * 32], 1u,
                                        __ATOMIC_RELAXED, __HIP_MEMORY_SCOPE_AGENT);
    if (a == epoch * 32u - 1u) {   // 32nd arrival of this epoch in this group
      unsigned t = __hip_atomic_fetch_add(&bar[0], 1u,
                                          __ATOMIC_RELAXED, __HIP_MEMORY_SCOPE_AGENT);
      if (t == epoch * 8u - 1u) {  // last group in: broadcast release
        #pragma unroll
        for (int gg = 0; gg < 8; ++gg)
          store_dword_wt(&bar[512 + gg * 32], epoch);
      }
    }
    while ((int)(__hip_atomic_load(&bar[512 + g * 32],
                                   __ATOMIC_RELAXED, __HIP_MEMORY_SCOPE_AGENT) - epoch) < 0)
      __builtin_amdgcn_s_sleep(4);
    __builtin_amdgcn_fence(__ATOMIC_ACQUIRE, "agent");   // buffer_inv only
  }
  __syncthreads();
}

// ---------- B-stream GEMM core: 16-batch tile, BOTH 16-row slices per wave ----------
// NCH chunks of CK=8 k-steps; per chunk 16 b16x8 loads (hi+lo) in flight while
// MFMAing the other buffer against A-slices 0 and 1 (LDS). Compile-time indices.
template<int NCH>
__device__ __forceinline__ void bstream(const __bf16* __restrict__ Bh,
                                        const __bf16* __restrict__ Bl,
                                        const b16x8* __restrict__ Ah0,
                                        const b16x8* __restrict__ Al0,
                                        const b16x8* __restrict__ Ah1,
                                        const b16x8* __restrict__ Al1,
                                        int aoff, int lr, int lg, f32x4* acc)
{
  constexpr int CK = 8;
  b16x8 bufA[CK][2], bufB[CK][2];

  auto load = [&](b16x8 (&buf)[CK][2], int ksb) {
    #pragma unroll
    for (int kk = 0; kk < CK; ++kk) {
      const size_t bo = (size_t)lr * K1 + (size_t)(ksb + kk) * 32;
      buf[kk][0] = *reinterpret_cast<const b16x8*>(Bh + bo);
      buf[kk][1] = *reinterpret_cast<const b16x8*>(Bl + bo);
    }
  };
  auto mm = [&](b16x8 (&buf)[CK][2], int ksb) {
    #pragma unroll
    for (int kk = 0; kk < CK; ++kk) {
      const int ac = (aoff + (ksb + kk) * 4 + lg) * 16 + lr;
      b16x8 ah0 = Ah0[ac], al0 = Al0[ac];
      b16x8 ah1 = Ah1[ac], al1 = Al1[ac];
      acc[0] = mfma16(ah0, buf[kk][0], acc[0]);
      acc[0] = mfma16(ah0, buf[kk][1], acc[0]);
      acc[0] = mfma16(al0, buf[kk][0], acc[0]);
      acc[1] = mfma16(ah1, buf[kk][0], acc[1]);
      acc[1] = mfma16(ah1, buf[kk][1], acc[1]);
      acc[1] = mfma16(al1, buf[kk][0], acc[1]);
    }
  };

  load(bufA, 0);
  #pragma unroll 1
  for (int cb = 0; cb < NCH; cb += 2) {
    if (cb + 1 < NCH) load(bufB, (cb + 1) * CK);
    mm(bufA, cb * CK);
    if (cb + 2 < NCH) load(bufA, (cb + 2) * CK);
    if (cb + 1 < NCH) mm(bufB, (cb + 1) * CK);
  }
}

// ---------- persistent MFMA LSTM ----------
// 256 wgs x 512 thr (8 waves, 2/SIMD). wg<128: layer1, rg=(wg&127)>>1, bg=wg&1;
// wg>=128: layer0 same on (wg-128). wg tile = 32 rows x 128 batch.
// Wave wv: batch block bv*16 (single 16-col B tile); computes BOTH 16-row
// slices (acc[2] by slice) -> B issued ONCE per byte per CU.
// Weights (split hi/lo) for the wg's 32 rows in 128 KB dynamic LDS, loaded ONCE.
// D layout: col=lane&15 (batch), row=(lane>>4)*4+reg. Rows permuted hcol*4+gate =>
// lane's 4 acc regs = i,f,g,o of one (hcol,batch): cell update lane-local, c in regs.
// Activations in1{hi,lo}[2][256][1024]: cols 0..511 = h0, 512..1023 = h1, k-major.
__global__ __launch_bounds__(NTHR, 2) void k_lstm(
    const __bf16* __restrict__ xhi, const __bf16* __restrict__ xlo,
    const __bf16* __restrict__ w0hi, const __bf16* __restrict__ w0lo, const float* __restrict__ bias0,
    const __bf16* __restrict__ w1hi, const __bf16* __restrict__ w1lo, const float* __restrict__ bias1,
    __bf16* __restrict__ in1hi, __bf16* __restrict__ in1lo,
    const float* __restrict__ fcw, const float* __restrict__ fcb,
    float* __restrict__ out, unsigned* __restrict__ bar)
{
  extern __shared__ __align__(16) __bf16 ldsA[];   // [hi 32*KW | lo 32*KW]

  const int tid  = threadIdx.x;
  const int lane = tid & 63;
  const int wv   = __builtin_amdgcn_readfirstlane(tid >> 6);   // 0..7
  const int wg   = blockIdx.x;
  const int layer1 = (wg < 128) ? 1 : 0;
  const int lw   = wg & 127;
  const int rg   = lw >> 1;            // 0..63 row-group (32 rows)
  const int bg   = lw & 1;             // 0..1 batch-group (128 batch)
  const int bbase = bg * 128 + wv * 16;
  const int lr = lane & 15;            // A-row16 / B-batch / D-col offset
  const int lg = lane >> 4;            // k-subgroup (A/B), row-subgroup (D)
  const int KW = layer1 ? K1 : K0;

  // ---- one-time: load this wg's 32-row weight slice into LDS ----
  {
    const b16x8* gh = reinterpret_cast<const b16x8*>((layer1 ? w1hi : w0hi) + (size_t)rg * 32 * KW);
    const b16x8* gl = reinterpret_cast<const b16x8*>((layer1 ? w1lo : w0lo) + (size_t)rg * 32 * KW);
    b16x8* lh = reinterpret_cast<b16x8*>(ldsA);
    b16x8* ll = reinterpret_cast<b16x8*>(ldsA + 32 * KW);
    const int nch = 4 * KW;            // 32*KW/8 chunks of 16 B
    for (int ch = tid; ch < nch; ch += NTHR) { lh[ch] = gh[ch]; ll[ch] = gl[ch]; }
  }
  __syncthreads();

  // lane's hidden columns (slice 0 and 1) and biases
  const int hc0 = rg * 8 + lg;
  const int hc1 = rg * 8 + 4 + lg;
  const float* bsrc = layer1 ? bias1 : bias0;
  const float4 b4A = *reinterpret_cast<const float4*>(bsrc + hc0 * 4);
  const float4 b4B = *reinterpret_cast<const float4*>(bsrc + hc1 * 4);
  const b16x8* Ah0 = reinterpret_cast<const b16x8*>(ldsA);
  const b16x8* Al0 = reinterpret_cast<const b16x8*>(ldsA + 32 * KW);
  const b16x8* Ah1 = Ah0 + (size_t)2 * KW;
  const b16x8* Al1 = Al0 + (size_t)2 * KW;

  float c[2] = {0.f, 0.f};

  #pragma unroll 1
  for (int n = 0; n <= T_SEQ; ++n) {
    const int pr = (n + 1) & 1;   // read parity
    const int pw = n & 1;         // write parity
    const bool active = layer1 ? (n >= 1) : (n < T_SEQ);
    if (active) {
      f32x4 acc[2];
      acc[0][0]=b4A.x; acc[0][1]=b4A.y; acc[0][2]=b4A.z; acc[0][3]=b4A.w;
      acc[1][0]=b4B.x; acc[1][1]=b4B.y; acc[1][2]=b4B.z; acc[1][3]=b4B.w;

      const __bf16* Bh = in1hi + ((size_t)pr * BATCH + bbase) * K1 + lg * 8;
      const __bf16* Bl = in1lo + ((size_t)pr * BATCH + bbase) * K1 + lg * 8;

      if (layer1) {
        bstream<4>(Bh, Bl, Ah0, Al0, Ah1, Al1, 0, lr, lg, acc);
      } else {
        const __bf16* Xh = xhi + ((size_t)n * BATCH + bbase) * IN0 + lg * 8;
        const __bf16* Xl = xlo + ((size_t)n * BATCH + bbase) * IN0 + lg * 8;
        #pragma unroll
        for (int ks = 0; ks < 2; ++ks) {            // x part: k 0..63
          const int ac = (ks * 4 + lg) * 16 + lr;
          b16x8 ah0 = Ah0[ac], al0 = Al0[ac];
          b16x8 ah1 = Ah1[ac], al1 = Al1[ac];
          const size_t bo = (size_t)lr * IN0 + ks * 32;
          b16x8 bh = *reinterpret_cast<const b16x8*>(Xh + bo);
          b16x8 bl = *reinterpret_cast<const b16x8*>(Xl + bo);
          acc[0] = mfma16(ah0, bh, acc[0]);
          acc[0] = mfma16(ah0, bl, acc[0]);
          acc[0] = mfma16(al0, bh, acc[0]);
          acc[1] = mfma16(ah1, bh, acc[1]);
          acc[1] = mfma16(ah1, bl, acc[1]);
          acc[1] = mfma16(al1, bh, acc[1]);
        }
        bstream<2>(Bh, Bl, Ah0, Al0, Ah1, Al1, 8, lr, lg, acc);  // h0 part
      }

      // ---- lane-local cell update; write-through split-bf16 h stores ----
      const int colb0 = layer1 ? (512 + hc0) : hc0;
      const int colb1 = layer1 ? (512 + hc1) : hc1;
      const int b = bbase + lr;
      #pragma unroll
      for (int sl = 0; sl < 2; ++sl) {
        float i_ = sigm(acc[sl][0]);
        float f_ = sigm(acc[sl][1]);
        float g_ = tanh_f(acc[sl][2]);
        float o_ = sigm(acc[sl][3]);
        c[sl] = fmaf(f_, c[sl], i_ * g_);
        float hv = o_ * tanh_f(c[sl]);
        __bf16 hh = (__bf16)hv;
        __bf16 hl = (__bf16)(hv - (float)hh);
        const size_t idx = ((size_t)pw * BATCH + b) * K1 + (sl ? colb1 : colb0);
        store_short_wt(in1hi + idx, (unsigned)__builtin_bit_cast(unsigned short, hh));
        store_short_wt(in1lo + idx, (unsigned)__builtin_bit_cast(unsigned short, hl));
      }
      asm volatile("s_waitcnt vmcnt(0)" ::: "memory");  // release: stores at coherence point
    }
    grid_barrier(bar, (unsigned)(n + 1));
  }

  // ---- final FC on h1[511] (written at iter 512, parity 0), cols 512..1023 ----
  if (wg == 0 && tid < BATCH) {
    const __bf16* rh = in1hi + (size_t)tid * K1 + 512;
    const __bf16* rl = in1lo + (size_t)tid * K1 + 512;
    float acc = 0.f;
    #pragma unroll 8
    for (int k = 0; k < HID; ++k)
      acc = fmaf((float)rh[k] + (float)rl[k], fcw[k], acc);
    out[tid] = acc + fcb[0];
  }
}

// ---------- host ----------
extern "C" void kernel_launch(void* const* d_in, const int* in_sizes, int n_in,
                              void* d_out, int out_size, void* d_ws, size_t ws_size,
                              hipStream_t stream) {
  const float* x    = (const float*)d_in[0];
  const float* Wih0 = (const float*)d_in[1];
  const float* Whh0 = (const float*)d_in[2];
  const float* bih0 = (const float*)d_in[3];
  const float* bhh0 = (const float*)d_in[4];
  const float* Wih1 = (const float*)d_in[5];
  const float* Whh1 = (const float*)d_in[6];
  const float* bih1 = (const float*)d_in[7];
  const float* bhh1 = (const float*)d_in[8];
  const float* fcw  = (const float*)d_in[9];
  const float* fcb  = (const float*)d_in[10];

  char* ws = (char*)d_ws;
  size_t off = 0;
  auto alloc = [&](size_t bytes) -> char* {
    char* pp = ws + off;
    off = (off + bytes + 1023) & ~(size_t)1023;
    return pp;
  };
  unsigned* bar  = (unsigned*)alloc(4096);
  __bf16* xhi  = (__bf16*)alloc((size_t)T_SEQ * BATCH * IN0 * 2);   // 16.8 MB
  __bf16* xlo  = (__bf16*)alloc((size_t)T_SEQ * BATCH * IN0 * 2);
  __bf16* w0hi = (__bf16*)alloc((size_t)2048 * K0 * 2);             // 2.36 MB
  __bf16* w0lo = (__bf16*)alloc((size_t)2048 * K0 * 2);
  __bf16* w1hi = (__bf16*)alloc((size_t)2048 * K1 * 2);             // 4.2 MB
  __bf16* w1lo = (__bf16*)alloc((size_t)2048 * K1 * 2);
  float*  bias0 = (float*)alloc(2048 * 4);
  float*  bias1 = (float*)alloc(2048 * 4);
  __bf16* in1hi = (__bf16*)alloc((size_t)2 * BATCH * K1 * 2);       // 1 MB
  __bf16* in1lo = (__bf16*)alloc((size_t)2 * BATCH * K1 * 2);

  static bool attr_done = false;
  if (!attr_done) {
    (void)hipFuncSetAttribute(reinterpret_cast<const void*>(k_lstm),
                              hipFuncAttributeMaxDynamicSharedMemorySize, LDS_DYN);
    attr_done = true;
  }

  (void)hipMemsetAsync(bar, 0, 4096, stream);
  (void)hipMemsetAsync(in1hi, 0, (size_t)2 * BATCH * K1 * 2, stream);
  (void)hipMemsetAsync(in1lo, 0, (size_t)2 * BATCH * K1 * 2, stream);
  k_split_x<<<(T_SEQ * BATCH * IN0) / 256, 256, 0, stream>>>(x, xhi, xlo);
  k_split_w<<<(int)((2048L * K0 + 255) / 256), 256, 0, stream>>>(Wih0, Whh0, bih0, bhh0, w0hi, w0lo, bias0, IN0);
  k_split_w<<<(int)((2048L * K1 + 255) / 256), 256, 0, stream>>>(Wih1, Whh1, bih1, bhh1, w1hi, w1lo, bias1, HID);
  k_lstm<<<NWG, NTHR, LDS_DYN, stream>>>(xhi, xlo, w0hi, w0lo, bias0, w1hi, w1lo, bias1,
                                         in1hi, in1lo, fcw, fcb, (float*)d_out, bar);
}

// Round 11
// 5986.691 us; speedup vs baseline: 5.1818x; 1.6209x over previous
//
#include <hip/hip_runtime.h>
#include <math.h>

#define T_SEQ 512
#define BATCH 256
#define HID   512
#define IN0   64
#define K1    1024           /* L1: 512 h0 + 512 h1 */
#define K0    576            /* L0: 64 x + 512 h0   */
#define NWG   256
#define NTHR  512
#define LDS_DYN 131072

typedef _Float16 f16x8 __attribute__((ext_vector_type(8)));
typedef float    f32x4 __attribute__((ext_vector_type(4)));

__device__ __forceinline__ float sigm(float x)   { return 1.0f / (1.0f + __expf(-x)); }
__device__ __forceinline__ float tanh_f(float x) { return 2.0f / (1.0f + __expf(-2.0f * x)) - 1.0f; }

__device__ __forceinline__ f32x4 mfma16(f16x8 a, f16x8 b, f32x4 c) {
  return __builtin_amdgcn_mfma_f32_16x16x32_f16(a, b, c, 0, 0, 0);
}

// write-through stores to the coherence point (no dirty L2 anywhere)
__device__ __forceinline__ void store_short_wt(const _Float16* p, unsigned v) {
  asm volatile("global_store_short %0, %1, off sc0 sc1"
               :: "v"((const void*)p), "v"(v) : "memory");
}
__device__ __forceinline__ void store_dword_wt(const unsigned* p, unsigned v) {
  asm volatile("global_store_dword %0, %1, off sc0 sc1"
               :: "v"((const void*)p), "v"(v) : "memory");
}

// ---------- prep: split W (fp16 hi + fp16 lo*1024) into LDS-order layout ----------
// rows permuted r = hcol*4 + gate; k-concat ih|hh.
// out layout: [slice s=r>>4][kc=k>>3][row16=r&15][ke=k&7]  (16-B chunks contiguous)
__global__ void k_split_w(const float* __restrict__ Wih, const float* __restrict__ Whh,
                          const float* __restrict__ bih, const float* __restrict__ bhh,
                          _Float16* __restrict__ whi, _Float16* __restrict__ wlo,
                          float* __restrict__ bias, int Kin) {
  int K = Kin + HID;
  long idx = (long)blockIdx.x * 256 + threadIdx.x;
  long total = 2048L * K;
  if (idx < total) {
    int k = (int)(idx % K);
    int r = (int)(idx / K);
    int gate = r & 3, hcol = r >> 2;
    int row = gate * HID + hcol;
    float v = (k < Kin) ? Wih[(long)row * Kin + k] : Whh[(long)row * HID + (k - Kin)];
    _Float16 h = (_Float16)v;
    long o = (long)(r >> 4) * 16 * K + (long)(k >> 3) * 128 + (r & 15) * 8 + (k & 7);
    whi[o] = h;
    wlo[o] = (_Float16)((v - (float)h) * 1024.0f);   // scaled residual, fp16-normal range
  }
  if (idx < 2048) {
    int r = (int)idx;
    int gate = r & 3, hcol = r >> 2;
    int row = gate * HID + hcol;
    bias[r] = bih[row] + bhh[row];
  }
}

// ---------- prep: x[B][T][I] -> fp16 [T][B][I] ----------
__global__ void k_split_x(const float* __restrict__ x, _Float16* __restrict__ x16) {
  int idx = blockIdx.x * 256 + threadIdx.x;   // dst index, [t][b][i]
  int i = idx & 63;
  int b = (idx >> 6) & 255;
  int t = idx >> 14;
  x16[idx] = (_Float16)x[((size_t)b * T_SEQ + t) * IN0 + i];
}

// ---------- two-level tree grid barrier + mirrored release lines ----------
// bar[0]          : top counter; epoch e complete when top hits 8*e
// bar[32+g*32]    : per-group arrival counter (g = wg&7, 32 members each)
// bar[512+g*32]   : per-group release mirror (polled line, one per group)
// All counters monotonic -> no reset race. Data release ordering comes from
// callers' s_waitcnt vmcnt(0) after write-through stores; acquire fence
// (buffer_inv only) makes peers' WT stores visible after release.
__device__ __forceinline__ void grid_barrier(unsigned* bar, unsigned epoch) {
  __syncthreads();
  if (threadIdx.x == 0) {
    const unsigned g = blockIdx.x & 7;
    unsigned a = __hip_atomic_fetch_add(&bar[32 + g * 32], 1u,
                                        __ATOMIC_RELAXED, __HIP_MEMORY_SCOPE_AGENT);
    if (a == epoch * 32u - 1u) {   // 32nd arrival of this epoch in this group
      unsigned t = __hip_atomic_fetch_add(&bar[0], 1u,
                                          __ATOMIC_RELAXED, __HIP_MEMORY_SCOPE_AGENT);
      if (t == epoch * 8u - 1u) {  // last group in: broadcast release
        #pragma unroll
        for (int gg = 0; gg < 8; ++gg)
          store_dword_wt(&bar[512 + gg * 32], epoch);
      }
    }
    while ((int)(__hip_atomic_load(&bar[512 + g * 32],
                                   __ATOMIC_RELAXED, __HIP_MEMORY_SCOPE_AGENT) - epoch) < 0)
      __builtin_amdgcn_s_sleep(4);
    __builtin_amdgcn_fence(__ATOMIC_ACQUIRE, "agent");   // buffer_inv only
  }
  __syncthreads();
}

// ---------- persistent MFMA LSTM (fp16 activations, dual-accumulator weights) ----------
// 256 wgs x 512 thr (8 waves, 2/SIMD). wg<128: layer1, rg=(wg&127)>>1, bg=wg&1;
// wg>=128: layer0 same on (wg-128). wg tile = 32 rows x 128 batch.
// Wave wv: batch block wv*16 (single 16-col fp16 B tile); computes BOTH 16-row
// slices. Per k-step: 1 B-load + 4 MFMAs (wh->accH, wl'*1024->accL, x2 slices).
// Final: acc = accH + accL/1024  (full weight precision, no denormal reliance).
// Weights (wh | wl') for the wg's 32 rows in 128 KB dynamic LDS, loaded ONCE.
// D layout: col=lane&15 (batch), row=(lane>>4)*4+reg. Rows permuted hcol*4+gate =>
// lane's 4 acc regs = i,f,g,o of one (hcol,batch): cell update lane-local, c in regs.
// Activations in1 (fp16) [2][256][1024]: cols 0..511 = h0, 512..1023 = h1, k-major.
__global__ __launch_bounds__(NTHR, 2) void k_lstm(
    const _Float16* __restrict__ x16,
    const _Float16* __restrict__ w0hi, const _Float16* __restrict__ w0lo, const float* __restrict__ bias0,
    const _Float16* __restrict__ w1hi, const _Float16* __restrict__ w1lo, const float* __restrict__ bias1,
    _Float16* __restrict__ in1,
    const float* __restrict__ fcw, const float* __restrict__ fcb,
    float* __restrict__ out, unsigned* __restrict__ bar)
{
  extern __shared__ __align__(16) _Float16 ldsA[];   // [wh 32*KW | wl' 32*KW]

  const int tid  = threadIdx.x;
  const int lane = tid & 63;
  const int wv   = __builtin_amdgcn_readfirstlane(tid >> 6);   // 0..7
  const int wg   = blockIdx.x;
  const int layer1 = (wg < 128) ? 1 : 0;
  const int lw   = wg & 127;
  const int rg   = lw >> 1;            // 0..63 row-group (32 rows)
  const int bg   = lw & 1;             // 0..1 batch-group (128 batch)
  const int bbase = bg * 128 + wv * 16;
  const int lr = lane & 15;            // A-row16 / B-batch / D-col offset
  const int lg = lane >> 4;            // k-subgroup (A/B), row-subgroup (D)
  const int KW = layer1 ? K1 : K0;

  // ---- one-time: load this wg's 32-row weight slice into LDS ----
  {
    const f16x8* gh = reinterpret_cast<const f16x8*>((layer1 ? w1hi : w0hi) + (size_t)rg * 32 * KW);
    const f16x8* gl = reinterpret_cast<const f16x8*>((layer1 ? w1lo : w0lo) + (size_t)rg * 32 * KW);
    f16x8* lh = reinterpret_cast<f16x8*>(ldsA);
    f16x8* ll = reinterpret_cast<f16x8*>(ldsA + 32 * KW);
    const int nch = 4 * KW;            // 32*KW/8 chunks of 16 B
    for (int ch = tid; ch < nch; ch += NTHR) { lh[ch] = gh[ch]; ll[ch] = gl[ch]; }
  }
  __syncthreads();

  // lane's hidden columns (slice 0 and 1) and biases
  const int hc0 = rg * 8 + lg;
  const int hc1 = rg * 8 + 4 + lg;
  const float* bsrc = layer1 ? bias1 : bias0;
  const float4 b4A = *reinterpret_cast<const float4*>(bsrc + hc0 * 4);
  const float4 b4B = *reinterpret_cast<const float4*>(bsrc + hc1 * 4);
  const f16x8* Ah0 = reinterpret_cast<const f16x8*>(ldsA);
  const f16x8* Al0 = reinterpret_cast<const f16x8*>(ldsA + 32 * KW);
  const f16x8* Ah1 = Ah0 + (size_t)2 * KW;
  const f16x8* Al1 = Al0 + (size_t)2 * KW;

  float c[2] = {0.f, 0.f};

  #pragma unroll 1
  for (int n = 0; n <= T_SEQ; ++n) {
    const int pr = (n + 1) & 1;   // read parity
    const int pw = n & 1;         // write parity
    const bool active = layer1 ? (n >= 1) : (n < T_SEQ);
    if (active) {
      f32x4 accH[2], accL[2];
      accH[0][0]=b4A.x; accH[0][1]=b4A.y; accH[0][2]=b4A.z; accH[0][3]=b4A.w;
      accH[1][0]=b4B.x; accH[1][1]=b4B.y; accH[1][2]=b4B.z; accH[1][3]=b4B.w;
      accL[0] = (f32x4){0.f,0.f,0.f,0.f};
      accL[1] = (f32x4){0.f,0.f,0.f,0.f};

      const _Float16* Bp = in1 + ((size_t)pr * BATCH + bbase) * K1 + lg * 8;

      if (layer1) {
        // 32 k-steps; issue ALL 32 loads (512 B/lane in flight), then 2 MFMA blocks
        f16x8 bufA[16], bufB[16];
        #pragma unroll
        for (int kk = 0; kk < 16; ++kk)
          bufA[kk] = *reinterpret_cast<const f16x8*>(Bp + (size_t)lr * K1 + (size_t)kk * 32);
        #pragma unroll
        for (int kk = 0; kk < 16; ++kk)
          bufB[kk] = *reinterpret_cast<const f16x8*>(Bp + (size_t)lr * K1 + (size_t)(16 + kk) * 32);
        #pragma unroll
        for (int kk = 0; kk < 16; ++kk) {
          const int ac = (kk * 4 + lg) * 16 + lr;
          accH[0] = mfma16(Ah0[ac], bufA[kk], accH[0]);
          accL[0] = mfma16(Al0[ac], bufA[kk], accL[0]);
          accH[1] = mfma16(Ah1[ac], bufA[kk], accH[1]);
          accL[1] = mfma16(Al1[ac], bufA[kk], accL[1]);
        }
        #pragma unroll
        for (int kk = 0; kk < 16; ++kk) {
          const int ac = ((16 + kk) * 4 + lg) * 16 + lr;
          accH[0] = mfma16(Ah0[ac], bufB[kk], accH[0]);
          accL[0] = mfma16(Al0[ac], bufB[kk], accL[0]);
          accH[1] = mfma16(Ah1[ac], bufB[kk], accH[1]);
          accL[1] = mfma16(Al1[ac], bufB[kk], accL[1]);
        }
      } else {
        // x part (2 k-steps) + h0 part (16 k-steps); loads issued before MFMAs
        const _Float16* Xp = x16 + ((size_t)n * BATCH + bbase) * IN0 + lg * 8;
        f16x8 xb[2];
        xb[0] = *reinterpret_cast<const f16x8*>(Xp + (size_t)lr * IN0);
        xb[1] = *reinterpret_cast<const f16x8*>(Xp + (size_t)lr * IN0 + 32);
        f16x8 bufA[16];
        #pragma unroll
        for (int kk = 0; kk < 16; ++kk)
          bufA[kk] = *reinterpret_cast<const f16x8*>(Bp + (size_t)lr * K1 + (size_t)kk * 32);
        #pragma unroll
        for (int ks = 0; ks < 2; ++ks) {
          const int ac = (ks * 4 + lg) * 16 + lr;
          accH[0] = mfma16(Ah0[ac], xb[ks], accH[0]);
          accL[0] = mfma16(Al0[ac], xb[ks], accL[0]);
          accH[1] = mfma16(Ah1[ac], xb[ks], accH[1]);
          accL[1] = mfma16(Al1[ac], xb[ks], accL[1]);
        }
        #pragma unroll
        for (int kk = 0; kk < 16; ++kk) {
          const int ac = (8 + kk * 4 + lg) * 16 + lr;   // weight k-offset 64
          accH[0] = mfma16(Ah0[ac], bufA[kk], accH[0]);
          accL[0] = mfma16(Al0[ac], bufA[kk], accL[0]);
          accH[1] = mfma16(Ah1[ac], bufA[kk], accH[1]);
          accL[1] = mfma16(Al1[ac], bufA[kk], accL[1]);
        }
      }

      // ---- lane-local cell update; write-through fp16 h stores ----
      const int colb0 = layer1 ? (512 + hc0) : hc0;
      const int colb1 = layer1 ? (512 + hc1) : hc1;
      const int b = bbase + lr;
      #pragma unroll
      for (int sl = 0; sl < 2; ++sl) {
        const float s = 0.0009765625f;   // 1/1024
        float i_ = sigm(accH[sl][0] + accL[sl][0] * s);
        float f_ = sigm(accH[sl][1] + accL[sl][1] * s);
        float g_ = tanh_f(accH[sl][2] + accL[sl][2] * s);
        float o_ = sigm(accH[sl][3] + accL[sl][3] * s);
        c[sl] = fmaf(f_, c[sl], i_ * g_);
        float hv = o_ * tanh_f(c[sl]);
        _Float16 h16 = (_Float16)hv;
        const size_t idx = ((size_t)pw * BATCH + b) * K1 + (sl ? colb1 : colb0);
        store_short_wt(in1 + idx, (unsigned)__builtin_bit_cast(unsigned short, h16));
      }
      asm volatile("s_waitcnt vmcnt(0)" ::: "memory");  // release: stores at coherence point
    }
    grid_barrier(bar, (unsigned)(n + 1));
  }

  // ---- final FC on h1[511] (written at iter 512, parity 0), cols 512..1023 ----
  if (wg == 0 && tid < BATCH) {
    const _Float16* r = in1 + (size_t)tid * K1 + 512;
    float acc = 0.f;
    #pragma unroll 8
    for (int k = 0; k < HID; ++k)
      acc = fmaf((float)r[k], fcw[k], acc);
    out[tid] = acc + fcb[0];
  }
}

// ---------- host ----------
extern "C" void kernel_launch(void* const* d_in, const int* in_sizes, int n_in,
                              void* d_out, int out_size, void* d_ws, size_t ws_size,
                              hipStream_t stream) {
  const float* x    = (const float*)d_in[0];
  const float* Wih0 = (const float*)d_in[1];
  const float* Whh0 = (const float*)d_in[2];
  const float* bih0 = (const float*)d_in[3];
  const float* bhh0 = (const float*)d_in[4];
  const float* Wih1 = (const float*)d_in[5];
  const float* Whh1 = (const float*)d_in[6];
  const float* bih1 = (const float*)d_in[7];
  const float* bhh1 = (const float*)d_in[8];
  const float* fcw  = (const float*)d_in[9];
  const float* fcb  = (const float*)d_in[10];

  char* ws = (char*)d_ws;
  size_t off = 0;
  auto alloc = [&](size_t bytes) -> char* {
    char* pp = ws + off;
    off = (off + bytes + 1023) & ~(size_t)1023;
    return pp;
  };
  unsigned*  bar  = (unsigned*)alloc(4096);
  _Float16* x16  = (_Float16*)alloc((size_t)T_SEQ * BATCH * IN0 * 2);   // 16.8 MB
  _Float16* w0hi = (_Float16*)alloc((size_t)2048 * K0 * 2);             // 2.36 MB
  _Float16* w0lo = (_Float16*)alloc((size_t)2048 * K0 * 2);
  _Float16* w1hi = (_Float16*)alloc((size_t)2048 * K1 * 2);             // 4.2 MB
  _Float16* w1lo = (_Float16*)alloc((size_t)2048 * K1 * 2);
  float*    bias0 = (float*)alloc(2048 * 4);
  float*    bias1 = (float*)alloc(2048 * 4);
  _Float16* in1  = (_Float16*)alloc((size_t)2 * BATCH * K1 * 2);        // 1 MB

  static bool attr_done = false;
  if (!attr_done) {
    (void)hipFuncSetAttribute(reinterpret_cast<const void*>(k_lstm),
                              hipFuncAttributeMaxDynamicSharedMemorySize, LDS_DYN);
    attr_done = true;
  }

  (void)hipMemsetAsync(bar, 0, 4096, stream);
  (void)hipMemsetAsync(in1, 0, (size_t)2 * BATCH * K1 * 2, stream);
  k_split_x<<<(T_SEQ * BATCH * IN0) / 256, 256, 0, stream>>>(x, x16);
  k_split_w<<<(int)((2048L * K0 + 255) / 256), 256, 0, stream>>>(Wih0, Whh0, bih0, bhh0, w0hi, w0lo, bias0, IN0);
  k_split_w<<<(int)((2048L * K1 + 255) / 256), 256, 0, stream>>>(Wih1, Whh1, bih1, bhh1, w1hi, w1lo, bias1, HID);
  k_lstm<<<NWG, NTHR, LDS_DYN, stream>>>(x16, w0hi, w0lo, bias0, w1hi, w1lo, bias1,
                                         in1, fcw, fcb, (float*)d_out, bar);
}

// Round 12
// 4817.012 us; speedup vs baseline: 6.4401x; 1.2428x over previous
//
#include <hip/hip_runtime.h>
#include <math.h>

#define T_SEQ 512
#define BATCH 256
#define HID   512
#define IN0   64
#define K1    1024           /* L1: 512 h0 + 512 h1 */
#define K0    576            /* L0: 64 x + 512 h0   */
#define NWG   256
#define NTHR  256
#define LDS_DYN 131072

typedef _Float16 f16x8 __attribute__((ext_vector_type(8)));
typedef float    f32x4 __attribute__((ext_vector_type(4)));

__device__ __forceinline__ float sigm(float x)   { return 1.0f / (1.0f + __expf(-x)); }
__device__ __forceinline__ float tanh_f(float x) { return 2.0f / (1.0f + __expf(-2.0f * x)) - 1.0f; }

__device__ __forceinline__ f32x4 mfma16(f16x8 a, f16x8 b, f32x4 c) {
  return __builtin_amdgcn_mfma_f32_16x16x32_f16(a, b, c, 0, 0, 0);
}

// write-through stores to the coherence point (no dirty L2 anywhere)
__device__ __forceinline__ void store_short_wt(const _Float16* p, unsigned v) {
  asm volatile("global_store_short %0, %1, off sc0 sc1"
               :: "v"((const void*)p), "v"(v) : "memory");
}
__device__ __forceinline__ void store_dword_wt(const unsigned* p, unsigned v) {
  asm volatile("global_store_dword %0, %1, off sc0 sc1"
               :: "v"((const void*)p), "v"(v) : "memory");
}

// ---------- prep: W -> fp16, rows permuted r = hcol*4 + gate, k-concat ih|hh ----------
// out layout: [slice s=r>>4][kc=k>>3][row16=r&15][ke=k&7]  (16-B chunks contiguous)
__global__ void k_split_w(const float* __restrict__ Wih, const float* __restrict__ Whh,
                          const float* __restrict__ bih, const float* __restrict__ bhh,
                          _Float16* __restrict__ whi, float* __restrict__ bias, int Kin) {
  int K = Kin + HID;
  long idx = (long)blockIdx.x * 256 + threadIdx.x;
  long total = 2048L * K;
  if (idx < total) {
    int k = (int)(idx % K);
    int r = (int)(idx / K);
    int gate = r & 3, hcol = r >> 2;
    int row = gate * HID + hcol;
    float v = (k < Kin) ? Wih[(long)row * Kin + k] : Whh[(long)row * HID + (k - Kin)];
    long o = (long)(r >> 4) * 16 * K + (long)(k >> 3) * 128 + (r & 15) * 8 + (k & 7);
    whi[o] = (_Float16)v;
  }
  if (idx < 2048) {
    int r = (int)idx;
    int gate = r & 3, hcol = r >> 2;
    int row = gate * HID + hcol;
    bias[r] = bih[row] + bhh[row];
  }
}

// ---------- prep: x[B][T][I] -> fp16 [T][B][I] ----------
__global__ void k_split_x(const float* __restrict__ x, _Float16* __restrict__ x16) {
  int idx = blockIdx.x * 256 + threadIdx.x;   // dst index, [t][b][i]
  int i = idx & 63;
  int b = (idx >> 6) & 255;
  int t = idx >> 14;
  x16[idx] = (_Float16)x[((size_t)b * T_SEQ + t) * IN0 + i];
}

// ---------- two-level tree grid barrier + mirrored release lines ----------
// bar[0]          : top counter; epoch e complete when top hits 8*e
// bar[32+g*32]    : per-group arrival counter (g = wg&7, 32 members each)
// bar[512+g*32]   : per-group release mirror (polled line, one per group)
// All counters monotonic -> no reset race. Data release ordering comes from
// callers' s_waitcnt vmcnt(0) after write-through stores; acquire fence
// (buffer_inv only) makes peers' WT stores visible after release.
__device__ __forceinline__ void grid_barrier(unsigned* bar, unsigned epoch) {
  __syncthreads();
  if (threadIdx.x == 0) {
    const unsigned g = blockIdx.x & 7;
    unsigned a = __hip_atomic_fetch_add(&bar[32 + g * 32], 1u,
                                        __ATOMIC_RELAXED, __HIP_MEMORY_SCOPE_AGENT);
    if (a == epoch * 32u - 1u) {   // 32nd arrival of this epoch in this group
      unsigned t = __hip_atomic_fetch_add(&bar[0], 1u,
                                          __ATOMIC_RELAXED, __HIP_MEMORY_SCOPE_AGENT);
      if (t == epoch * 8u - 1u) {  // last group in: broadcast release
        #pragma unroll
        for (int gg = 0; gg < 8; ++gg)
          store_dword_wt(&bar[512 + gg * 32], epoch);
      }
    }
    while ((int)(__hip_atomic_load(&bar[512 + g * 32],
                                   __ATOMIC_RELAXED, __HIP_MEMORY_SCOPE_AGENT) - epoch) < 0)
      __builtin_amdgcn_s_sleep(4);
    __builtin_amdgcn_fence(__ATOMIC_ACQUIRE, "agent");   // buffer_inv only
  }
  __syncthreads();
}

// ---------- persistent MFMA LSTM (fp16 weights+activations, 64-row tiles) ----------
// 256 wgs x 256 thr (4 waves, 1/SIMD). wg<128: layer1, rg=(wg&127)>>2, bg=wg&3;
// wg>=128: layer0 same on (wg-128). wg tile = 64 rows x 64 batch.
// Wave wv: batch block bg*64+wv*16 (EXCLUSIVE 16-col B tile -> B issued once per
// byte per CU); computes all 4 row-slices: acc[4], c[4].
// fp16 weights for the wg's 64 rows in 128 KB dynamic LDS, loaded ONCE.
// D layout: col=lane&15 (batch), row=(lane>>4)*4+reg. Rows permuted hcol*4+gate =>
// lane's 4 acc regs = i,f,g,o of one (hcol,batch): cell update lane-local, c in regs.
// Activations in1 (fp16) [2][256][1024]: cols 0..511 = h0, 512..1023 = h1, k-major.
__global__ __launch_bounds__(NTHR, 1) void k_lstm(
    const _Float16* __restrict__ x16,
    const _Float16* __restrict__ w0, const float* __restrict__ bias0,
    const _Float16* __restrict__ w1, const float* __restrict__ bias1,
    _Float16* __restrict__ in1,
    const float* __restrict__ fcw, const float* __restrict__ fcb,
    float* __restrict__ out, unsigned* __restrict__ bar)
{
  extern __shared__ __align__(16) _Float16 ldsA[];   // 64 rows x KW fp16

  const int tid  = threadIdx.x;
  const int lane = tid & 63;
  const int wv   = __builtin_amdgcn_readfirstlane(tid >> 6);   // 0..3
  const int wg   = blockIdx.x;
  const int layer1 = (wg < 128) ? 1 : 0;
  const int lw   = wg & 127;
  const int rg   = lw >> 2;            // 0..31 row-group (64 rows)
  const int bg   = lw & 3;             // 0..3 batch-group (64 batch)
  const int bbase = bg * 64 + wv * 16;
  const int lr = lane & 15;            // A-row16 / B-batch / D-col offset
  const int lg = lane >> 4;            // k-subgroup (A/B), row-subgroup (D)
  const int KW = layer1 ? K1 : K0;

  // ---- one-time: load this wg's 64-row weight slice into LDS ----
  {
    const f16x8* gw = reinterpret_cast<const f16x8*>((layer1 ? w1 : w0) + (size_t)rg * 64 * KW);
    f16x8* lw16 = reinterpret_cast<f16x8*>(ldsA);
    const int nch = 8 * KW;            // 64*KW/8 chunks of 16 B
    for (int ch = tid; ch < nch; ch += NTHR) lw16[ch] = gw[ch];
  }
  __syncthreads();

  // lane's hidden columns (4 row-slices) and biases
  const float* bsrc = layer1 ? bias1 : bias0;
  float4 b4[4];
  int hcv[4];
  #pragma unroll
  for (int sl = 0; sl < 4; ++sl) {
    hcv[sl] = rg * 16 + sl * 4 + lg;
    b4[sl] = *reinterpret_cast<const float4*>(bsrc + hcv[sl] * 4);
  }
  const f16x8* A = reinterpret_cast<const f16x8*>(ldsA);   // slice sl at sl*2*KW (f16x8 units)

  float c[4] = {0.f, 0.f, 0.f, 0.f};

  #pragma unroll 1
  for (int n = 0; n <= T_SEQ; ++n) {
    const int pr = (n + 1) & 1;   // read parity
    const int pw = n & 1;         // write parity
    const bool active = layer1 ? (n >= 1) : (n < T_SEQ);
    if (active) {
      f32x4 acc[4];
      #pragma unroll
      for (int sl = 0; sl < 4; ++sl) {
        acc[sl][0]=b4[sl].x; acc[sl][1]=b4[sl].y; acc[sl][2]=b4[sl].z; acc[sl][3]=b4[sl].w;
      }

      const _Float16* Bp = in1 + ((size_t)pr * BATCH + bbase) * K1 + (size_t)lr * K1 + lg * 8;

      if (layer1) {
        // 32 k-chunks; issue ALL loads (512 B/lane in flight), then MFMA blocks
        f16x8 bufA[16], bufB[16];
        #pragma unroll
        for (int kk = 0; kk < 16; ++kk)
          bufA[kk] = *reinterpret_cast<const f16x8*>(Bp + (size_t)kk * 32);
        #pragma unroll
        for (int kk = 0; kk < 16; ++kk)
          bufB[kk] = *reinterpret_cast<const f16x8*>(Bp + (size_t)(16 + kk) * 32);
        #pragma unroll
        for (int kk = 0; kk < 16; ++kk) {
          const int ac = (kk * 4 + lg) * 16 + lr;
          #pragma unroll
          for (int sl = 0; sl < 4; ++sl)
            acc[sl] = mfma16(A[(size_t)sl * 2 * K1 + ac], bufA[kk], acc[sl]);
        }
        #pragma unroll
        for (int kk = 0; kk < 16; ++kk) {
          const int ac = ((16 + kk) * 4 + lg) * 16 + lr;
          #pragma unroll
          for (int sl = 0; sl < 4; ++sl)
            acc[sl] = mfma16(A[(size_t)sl * 2 * K1 + ac], bufB[kk], acc[sl]);
        }
      } else {
        // x part (2 k-chunks) + h0 part (16 k-chunks); loads issued before MFMAs
        const _Float16* Xp = x16 + ((size_t)n * BATCH + bbase) * IN0 + (size_t)lr * IN0 + lg * 8;
        f16x8 xb[2];
        xb[0] = *reinterpret_cast<const f16x8*>(Xp);
        xb[1] = *reinterpret_cast<const f16x8*>(Xp + 32);
        f16x8 bufA[16];
        #pragma unroll
        for (int kk = 0; kk < 16; ++kk)
          bufA[kk] = *reinterpret_cast<const f16x8*>(Bp + (size_t)kk * 32);
        #pragma unroll
        for (int ks = 0; ks < 2; ++ks) {
          const int ac = (ks * 4 + lg) * 16 + lr;
          #pragma unroll
          for (int sl = 0; sl < 4; ++sl)
            acc[sl] = mfma16(A[(size_t)sl * 2 * K0 + ac], xb[ks], acc[sl]);
        }
        #pragma unroll
        for (int kk = 0; kk < 16; ++kk) {
          const int ac = (8 + kk * 4 + lg) * 16 + lr;   // weight k-offset 64
          #pragma unroll
          for (int sl = 0; sl < 4; ++sl)
            acc[sl] = mfma16(A[(size_t)sl * 2 * K0 + ac], bufA[kk], acc[sl]);
        }
      }

      // ---- lane-local cell update; write-through fp16 h stores ----
      const int b = bbase + lr;
      #pragma unroll
      for (int sl = 0; sl < 4; ++sl) {
        float i_ = sigm(acc[sl][0]);
        float f_ = sigm(acc[sl][1]);
        float g_ = tanh_f(acc[sl][2]);
        float o_ = sigm(acc[sl][3]);
        c[sl] = fmaf(f_, c[sl], i_ * g_);
        float hv = o_ * tanh_f(c[sl]);
        _Float16 h16 = (_Float16)hv;
        const int col = (layer1 ? 512 : 0) + hcv[sl];
        const size_t idx = ((size_t)pw * BATCH + b) * K1 + col;
        store_short_wt(in1 + idx, (unsigned)__builtin_bit_cast(unsigned short, h16));
      }
      asm volatile("s_waitcnt vmcnt(0)" ::: "memory");  // release: stores at coherence point
    }
    grid_barrier(bar, (unsigned)(n + 1));
  }

  // ---- final FC on h1[511] (written at iter 512, parity 0), cols 512..1023 ----
  if (wg == 0 && tid < BATCH) {
    const _Float16* r = in1 + (size_t)tid * K1 + 512;
    float acc = 0.f;
    #pragma unroll 8
    for (int k = 0; k < HID; ++k)
      acc = fmaf((float)r[k], fcw[k], acc);
    out[tid] = acc + fcb[0];
  }
}

// ---------- host ----------
extern "C" void kernel_launch(void* const* d_in, const int* in_sizes, int n_in,
                              void* d_out, int out_size, void* d_ws, size_t ws_size,
                              hipStream_t stream) {
  const float* x    = (const float*)d_in[0];
  const float* Wih0 = (const float*)d_in[1];
  const float* Whh0 = (const float*)d_in[2];
  const float* bih0 = (const float*)d_in[3];
  const float* bhh0 = (const float*)d_in[4];
  const float* Wih1 = (const float*)d_in[5];
  const float* Whh1 = (const float*)d_in[6];
  const float* bih1 = (const float*)d_in[7];
  const float* bhh1 = (const float*)d_in[8];
  const float* fcw  = (const float*)d_in[9];
  const float* fcb  = (const float*)d_in[10];

  char* ws = (char*)d_ws;
  size_t off = 0;
  auto alloc = [&](size_t bytes) -> char* {
    char* pp = ws + off;
    off = (off + bytes + 1023) & ~(size_t)1023;
    return pp;
  };
  unsigned*  bar  = (unsigned*)alloc(4096);
  _Float16* x16  = (_Float16*)alloc((size_t)T_SEQ * BATCH * IN0 * 2);   // 16.8 MB
  _Float16* w0   = (_Float16*)alloc((size_t)2048 * K0 * 2);             // 2.36 MB
  _Float16* w1   = (_Float16*)alloc((size_t)2048 * K1 * 2);             // 4.2 MB
  float*    bias0 = (float*)alloc(2048 * 4);
  float*    bias1 = (float*)alloc(2048 * 4);
  _Float16* in1  = (_Float16*)alloc((size_t)2 * BATCH * K1 * 2);        // 1 MB

  (void)hipFuncSetAttribute(reinterpret_cast<const void*>(k_lstm),
                            hipFuncAttributeMaxDynamicSharedMemorySize, LDS_DYN);

  (void)hipMemsetAsync(bar, 0, 4096, stream);
  (void)hipMemsetAsync(in1, 0, (size_t)2 * BATCH * K1 * 2, stream);
  k_split_x<<<(T_SEQ * BATCH * IN0) / 256, 256, 0, stream>>>(x, x16);
  k_split_w<<<(int)((2048L * K0 + 255) / 256), 256, 0, stream>>>(Wih0, Whh0, bih0, bhh0, w0, bias0, IN0);
  k_split_w<<<(int)((2048L * K1 + 255) / 256), 256, 0, stream>>>(Wih1, Whh1, bih1, bhh1, w1, bias1, HID);
  k_lstm<<<NWG, NTHR, LDS_DYN, stream>>>(x16, w0, bias0, w1, bias1,
                                         in1, fcw, fcb, (float*)d_out, bar);
}